// Round 7
// baseline (912.973 us; speedup 1.0000x reference)
//
#include <hip/hip_runtime.h>
#include <math.h>

#define N_NODES 20000
#define N_EDGES 160000
#define DIM_IN  128
#define HIDDEN  96
#define NH      6
#define HD      576      // NH*HIDDEN
#define LDROW   1824     // bf16 row: Q(576) | K(576) | V(576) | S(96)
#define NALL    1824     // concat QKVS output cols
#define NGRAPH  512
#define NCLS    128
#define CHUNK   32       // edges per softmax chunk
#define SLD     104      // LDS stage row stride (ushorts)

typedef unsigned short ushort_t;
typedef __attribute__((ext_vector_type(8))) short bf16x8;
typedef __attribute__((ext_vector_type(4))) float f32x4;

static __device__ __forceinline__ ushort_t f2bf(float f) {
    unsigned int u = __float_as_uint(f);
    return (ushort_t)((u + 0x7fffu + ((u >> 16) & 1u)) >> 16);  // RNE
}
static __device__ __forceinline__ float bfs(ushort_t u) { return __uint_as_float((unsigned int)u << 16); }
static __device__ __forceinline__ float bflo(unsigned int u) { return __uint_as_float(u << 16); }
static __device__ __forceinline__ float bfhi(unsigned int u) { return __uint_as_float(u & 0xffff0000u); }

// ---------------------------------------------------------------------------
__global__ void k_cvt(const float* __restrict__ src, ushort_t* __restrict__ dst, int n)
{
    int i = blockIdx.x * blockDim.x + threadIdx.x;
    if (i < n) dst[i] = f2bf(src[i]);
}

// Build TRANSPOSED concat bf16 weights: WbT[n][k] = W*(k, n), n in [0,1824)
__global__ void k_cvt_wT(const float* __restrict__ Wq, const float* __restrict__ Wk,
                         const float* __restrict__ Wv, const float* __restrict__ Ws,
                         int K, ushort_t* __restrict__ dst)
{
    int i = blockIdx.x * blockDim.x + threadIdx.x;
    if (i >= K * NALL) return;
    int n = i / K, k = i - n * K;
    float v;
    if (n < 576)       v = Wq[(size_t)k * HD + n];
    else if (n < 1152) v = Wk[(size_t)k * HD + (n - 576)];
    else if (n < 1728) v = Wv[(size_t)k * HD + (n - 1152)];
    else               v = Ws[(size_t)k * HIDDEN + (n - 1728)];
    dst[i] = f2bf(v);
}

// ---------------------------------------------------------------------------
// bf16 MFMA fused QKVS projection. Block 128(M) x 96(N), 4 waves (2x2), each
// 64x48 via 4x3 mfma_f32_16x16x32_bf16. B pre-transposed -> staging is pure
// uint4 copies. Epilogue: bias + bf16 LDS stage (aliasing As) + uint4 stores.
// grid.x = 19 col-blocks of 96 -> one bf16 output row kvqs[1824] = Q|K|V|S.
// ---------------------------------------------------------------------------
template<int KDIM>
__global__ __launch_bounds__(256) void gemm_qkvs_mfma(
    const ushort_t* __restrict__ A, int M,
    const ushort_t* __restrict__ WbT,
    const float* __restrict__ bq, const float* __restrict__ bk,
    const float* __restrict__ bv, const float* __restrict__ bs,
    ushort_t* __restrict__ kvqs)
{
    constexpr int LDA = KDIM + 8;
    constexpr int K8  = KDIM >> 3;
    __shared__ __align__(16) ushort_t As[128 * LDA];   // >= 128*SLD for stage
    __shared__ __align__(16) ushort_t Bs[96 * LDA];
    const int t    = threadIdx.x;
    const int lane = t & 63;
    const int w    = t >> 6;
    const int wm   = w & 1, wn = w >> 1;
    const int quad = lane >> 4;
    const int l16  = lane & 15;
    const int m0   = blockIdx.y * 128;
    const int rb   = blockIdx.x;          // 0..18
    const int n0   = rb * 96;

    // stage A tile [128 x K] bf16
    for (int idx = t; idx < 128 * K8; idx += 256) {
        int r = idx / K8, kc = idx - r * K8;
        int row = m0 + r;
        uint4 v = make_uint4(0u, 0u, 0u, 0u);
        if (row < M) v = *(const uint4*)(A + (size_t)row * KDIM + kc * 8);
        *(uint4*)(&As[r * LDA + kc * 8]) = v;
    }
    // stage B tile [96 x K] from transposed weights: pure vector copies
    for (int idx = t; idx < 96 * K8; idx += 256) {
        int c = idx / K8, kc = idx - c * K8;
        uint4 v = *(const uint4*)(WbT + (size_t)(n0 + c) * KDIM + kc * 8);
        *(uint4*)(&Bs[c * LDA + kc * 8]) = v;
    }
    __syncthreads();

    f32x4 acc[4][3] = {};
    #pragma unroll
    for (int ks = 0; ks < KDIM; ks += 32) {
        bf16x8 af[4], bfv[3];
        #pragma unroll
        for (int i = 0; i < 4; i++)
            af[i] = *(const bf16x8*)(&As[(wm * 64 + i * 16 + l16) * LDA + ks + quad * 8]);
        #pragma unroll
        for (int j = 0; j < 3; j++)
            bfv[j] = *(const bf16x8*)(&Bs[(wn * 48 + j * 16 + l16) * LDA + ks + quad * 8]);
        #pragma unroll
        for (int i = 0; i < 4; i++)
            #pragma unroll
            for (int j = 0; j < 3; j++)
                acc[i][j] = __builtin_amdgcn_mfma_f32_16x16x32_bf16(af[i], bfv[j], acc[i][j], 0, 0, 0);
    }

    // bias select (region boundaries are multiples of 96)
    const float* biasp;
    int cb0;
    if (rb < 6)       { biasp = bq; cb0 = n0; }
    else if (rb < 12) { biasp = bk; cb0 = n0 - 576; }
    else if (rb < 18) { biasp = bv; cb0 = n0 - 1152; }
    else              { biasp = bs; cb0 = 0; }
    float bj[3];
    #pragma unroll
    for (int j = 0; j < 3; j++) bj[j] = biasp[cb0 + wn * 48 + j * 16 + l16];

    // stage results bf16 into As (aliased)
    __syncthreads();
    ushort_t* stage = As;
    #pragma unroll
    for (int i = 0; i < 4; i++) {
        #pragma unroll
        for (int r = 0; r < 4; r++) {
            int row = wm * 64 + i * 16 + quad * 4 + r;
            #pragma unroll
            for (int j = 0; j < 3; j++)
                stage[row * SLD + wn * 48 + j * 16 + l16] = f2bf(acc[i][j][r] + bj[j]);
        }
    }
    __syncthreads();

    // cooperative coalesced store: 128 rows x 12 uint4
    for (int idx = t; idx < 128 * 12; idx += 256) {
        int r = idx / 12, v = idx - r * 12;
        int row = m0 + r;
        if (row < M)
            *(uint4*)(kvqs + (size_t)row * LDROW + n0 + v * 8) =
                *(const uint4*)(&stage[r * SLD + v * 8]);
    }
}

// ---------------------------------------------------------------------------
// CSR construction by destination node
// ---------------------------------------------------------------------------
__global__ void k_deg(const int* __restrict__ edst, int* __restrict__ deg)
{
    int e = blockIdx.x * blockDim.x + threadIdx.x;
    if (e < N_EDGES) atomicAdd(&deg[edst[e]], 1);
}

__global__ __launch_bounds__(1024) void k_scan(const int* __restrict__ deg,
                                               int* __restrict__ row_ptr,
                                               int* __restrict__ cursor)
{
    __shared__ int part[1024];
    int t = threadIdx.x;
    const int chunk = (N_NODES + 1023) / 1024;  // 20
    int b = t * chunk;
    int s = 0;
    for (int i = 0; i < chunk; i++)
        if (b + i < N_NODES) s += deg[b + i];
    part[t] = s;
    __syncthreads();
    for (int o = 1; o < 1024; o <<= 1) {
        int v = (t >= o) ? part[t - o] : 0;
        __syncthreads();
        part[t] += v;
        __syncthreads();
    }
    int run = part[t] - s;
    for (int i = 0; i < chunk; i++) {
        if (b + i < N_NODES) {
            row_ptr[b + i] = run;
            cursor[b + i]  = run;
            run += deg[b + i];
        }
    }
    if (t == 1023) row_ptr[N_NODES] = part[1023];
}

__global__ void k_scatter(const int* __restrict__ esrc, const int* __restrict__ edst,
                          int* __restrict__ cursor, int* __restrict__ csrc)
{
    int e = blockIdx.x * blockDim.x + threadIdx.x;
    if (e < N_EDGES) {
        int pos = atomicAdd(&cursor[edst[e]], 1);
        csrc[pos] = esrc[e];
    }
}

// ---------------------------------------------------------------------------
// Fused per-destination-node attention.
// pass 1: 4 lanes per edge, each a 24-elem partial K-dot (3 uint4) + 2 shfl.
// pass 2: thread t<144 owns V elements 4t..4t+3 (one head) -> uint2 loads;
//         first 8 edges' V prefetched into registers during pass 1.
// ---------------------------------------------------------------------------
__global__ __launch_bounds__(192) void node_attn(
    const ushort_t* __restrict__ kvqs,
    const int* __restrict__ row_ptr, const int* __restrict__ csrc,
    ushort_t* __restrict__ hb, float* __restrict__ hf)
{
    const int n = blockIdx.x;
    const int t = threadIdx.x;
    const int lane = t & 31;
    const int g = t >> 5;              // head group 0..5
    const int el = lane >> 2;          // edge slot 0..7
    const int qr = lane & 3;           // quarter 0..3

    __shared__ float Qs[HD];
    __shared__ float wbuf[CHUNK * NH];
    __shared__ int   srcs[CHUNK];
    __shared__ float m[NH], l[NH], scale[NH], linv[NH];
    __shared__ float arr[HD];

    const int beg = row_ptr[n], end = row_ptr[n + 1];
    const ushort_t* qk = kvqs + (size_t)n * LDROW;

    // vectorized Q stage: 72 threads x uint4 (8 bf16 each)
    if (t < 72) {
        uint4 v = *(const uint4*)(qk + t * 8);
        unsigned int uu[4] = {v.x, v.y, v.z, v.w};
        #pragma unroll
        for (int j = 0; j < 4; j++) {
            Qs[t * 8 + 2 * j]     = bflo(uu[j]);
            Qs[t * 8 + 2 * j + 1] = bfhi(uu[j]);
        }
    }
    if (t < NH) { m[t] = -1e30f; l[t] = 0.f; }

    // pass-2 ownership: t<144 owns d = 4t..4t+3 (all in head hh)
    const int d4 = 4 * t;
    const int hh = d4 / HIDDEN;        // valid for t<144
    float a[4] = {0.f, 0.f, 0.f, 0.f};
    const float qa = 0.10206207261596577f; // 1/sqrt(96)

    for (int cb = beg; cb < end; cb += CHUNK) {
        const int c = min(CHUNK, end - cb);
        __syncthreads();
        if (t < c) srcs[t] = csrc[cb + t];
        __syncthreads();

        // ---- V prefetch for first up-to-8 edges (overlaps pass 1) -------
        uint2 pre[8];
        const int npre = min(c, 8);
        if (t < 144) {
            for (int j = 0; j < npre; j++)
                pre[j] = *(const uint2*)(kvqs + (size_t)srcs[j] * LDROW + 2 * HD + d4);
        }

        // ---- pass 1: logits, 4 lanes per edge ---------------------------
        for (int eb = 0; eb < c; eb += 8) {
            int e8 = eb + el;
            bool act = e8 < c;
            int src = srcs[act ? e8 : 0];
            const uint4* kp = (const uint4*)(kvqs + (size_t)src * LDROW + HD + g * HIDDEN + qr * 24);
            uint4 r0 = kp[0], r1 = kp[1], r2 = kp[2];
            const float* qb = &Qs[g * HIDDEN + qr * 24];
            float p = 0.f;
            unsigned int uu[12] = {r0.x, r0.y, r0.z, r0.w, r1.x, r1.y, r1.z, r1.w,
                                   r2.x, r2.y, r2.z, r2.w};
            #pragma unroll
            for (int k2 = 0; k2 < 12; k2++)
                p += bflo(uu[k2]) * qb[2 * k2] + bfhi(uu[k2]) * qb[2 * k2 + 1];
            p += __shfl_xor(p, 1, 32);
            p += __shfl_xor(p, 2, 32);
            if (act && qr == 0) wbuf[e8 * NH + g] = p * qa;
        }
        __syncthreads();

        // ---- softmax bookkeeping ---------------------------------------
        if (t < NH) {
            float cm = m[t];
            for (int e = 0; e < c; e++) cm = fmaxf(cm, wbuf[e * NH + t]);
            scale[t] = __expf(m[t] - cm);
            m[t] = cm;
            l[t] *= scale[t];
        }
        __syncthreads();

        float lp = 0.f;
        for (int e = lane; e < c; e += 32) {
            float w2 = __expf(wbuf[e * NH + g] - m[g]);
            wbuf[e * NH + g] = w2;
            lp += w2;
        }
        #pragma unroll
        for (int o = 16; o; o >>= 1) lp += __shfl_xor(lp, o, 32);
        if (lane == 0) l[g] += lp;
        __syncthreads();

        // ---- pass 2: V aggregation -------------------------------------
        if (t < 144) {
            float sc = scale[hh];
            #pragma unroll
            for (int j = 0; j < 4; j++) a[j] *= sc;
            for (int e = 0; e < npre; e++) {
                float w2 = wbuf[e * NH + hh];
                a[0] += w2 * bflo(pre[e].x);
                a[1] += w2 * bfhi(pre[e].x);
                a[2] += w2 * bflo(pre[e].y);
                a[3] += w2 * bfhi(pre[e].y);
            }
            for (int e = 8; e < c; e++) {
                uint2 v = *(const uint2*)(kvqs + (size_t)srcs[e] * LDROW + 2 * HD + d4);
                float w2 = wbuf[e * NH + hh];
                a[0] += w2 * bflo(v.x);
                a[1] += w2 * bfhi(v.x);
                a[2] += w2 * bflo(v.y);
                a[3] += w2 * bfhi(v.y);
            }
        }
    }

    if (t < NH) linv[t] = (l[t] > 0.f) ? 1.0f / l[t] : 0.f;
    __syncthreads();
    if (t < 144) {
        float li = linv[hh];
        #pragma unroll
        for (int j = 0; j < 4; j++) arr[d4 + j] = a[j] * li;
    }
    __syncthreads();

    if (t < HIDDEN) {
        float s = (arr[t] + arr[HIDDEN + t] + arr[2 * HIDDEN + t] +
                   arr[3 * HIDDEN + t] + arr[4 * HIDDEN + t] + arr[5 * HIDDEN + t])
                  * (1.0f / 6.0f);
        s += bfs(qk[3 * HD + t]);   // skip connection S (bf16)
        s = fmaxf(s, 0.0f);
        hb[n * HIDDEN + t] = f2bf(s);
        hf[n * HIDDEN + t] = s;
    }
}

// ---------------------------------------------------------------------------
__global__ void k_pool(const float* __restrict__ h, const int* __restrict__ batch,
                       float* __restrict__ gsum, int* __restrict__ gcnt)
{
    int i = blockIdx.x * blockDim.x + threadIdx.x;
    if (i >= N_NODES * HIDDEN) return;
    int n = i / HIDDEN, d = i - n * HIDDEN;
    int b = batch[n];
    atomicAdd(&gsum[b * HIDDEN + d], h[i]);
    if (d == 0) atomicAdd(&gcnt[b], 1);
}

__global__ __launch_bounds__(128) void k_head(
    const float* __restrict__ gsum, const int* __restrict__ gcnt,
    const float* __restrict__ fc1w, const float* __restrict__ fc1b,
    const float* __restrict__ fc2w, const float* __restrict__ fc2b,
    const float* __restrict__ arcw, float* __restrict__ out)
{
    int g = blockIdx.x, t = threadIdx.x;
    __shared__ float v0[HIDDEN], v1[HIDDEN], v2[HIDDEN];
    __shared__ float gnorm;
    float cnt = fmaxf((float)gcnt[g], 1.0f);
    if (t < HIDDEN) v0[t] = gsum[g * HIDDEN + t] / cnt;
    __syncthreads();
    if (t < HIDDEN) {
        float s = fc1b[t];
        for (int k = 0; k < HIDDEN; k++) s += v0[k] * fc1w[k * HIDDEN + t];
        v1[t] = fmaxf(s, 0.f);
    }
    __syncthreads();
    if (t < HIDDEN) {
        float s = fc2b[t];
        for (int k = 0; k < HIDDEN; k++) s += v1[k] * fc2w[k * HIDDEN + t];
        v2[t] = fmaxf(s, 0.f);
    }
    __syncthreads();
    if (t == 0) {
        float s = 0.f;
        for (int k = 0; k < HIDDEN; k++) s += v2[k] * v2[k];
        gnorm = sqrtf(s) + 1e-12f;
    }
    __syncthreads();
    if (t < NCLS) {
        float dot = 0.f, wn = 0.f;
        const float* wr = arcw + (size_t)t * HIDDEN;
        for (int k = 0; k < HIDDEN; k++) {
            float w = wr[k];
            dot += w * v2[k];
            wn  += w * w;
        }
        out[g * NCLS + t] = 30.0f * dot / (gnorm * (sqrtf(wn) + 1e-12f));
    }
}

// ---------------------------------------------------------------------------
extern "C" void kernel_launch(void* const* d_in, const int* in_sizes, int n_in,
                              void* d_out, int out_size, void* d_ws, size_t ws_size,
                              hipStream_t stream)
{
    (void)in_sizes; (void)n_in; (void)out_size; (void)ws_size;

    const float* x     = (const float*)d_in[0];
    const int*   ei    = (const int*)d_in[1];
    const int*   batch = (const int*)d_in[2];
    const float* Wq1 = (const float*)d_in[3];  const float* bq1 = (const float*)d_in[4];
    const float* Wk1 = (const float*)d_in[5];  const float* bk1 = (const float*)d_in[6];
    const float* Wv1 = (const float*)d_in[7];  const float* bv1 = (const float*)d_in[8];
    const float* Ws1 = (const float*)d_in[9];  const float* bs1 = (const float*)d_in[10];
    const float* Wq_r = (const float*)d_in[11]; const float* bq_r = (const float*)d_in[12];
    const float* Wk_r = (const float*)d_in[13]; const float* bk_r = (const float*)d_in[14];
    const float* Wv_r = (const float*)d_in[15]; const float* bv_r = (const float*)d_in[16];
    const float* Ws_r = (const float*)d_in[17]; const float* bs_r = (const float*)d_in[18];
    const float* fc1w = (const float*)d_in[19]; const float* fc1b = (const float*)d_in[20];
    const float* fc2w = (const float*)d_in[21]; const float* fc2b = (const float*)d_in[22];
    const float* arcw = (const float*)d_in[23];
    float* out = (float*)d_out;

    const int* esrc = ei;
    const int* edst = ei + N_EDGES;

    char* base = (char*)d_ws;
    size_t off = 0;
    auto alloc = [&](size_t bytes) -> void* {
        off = (off + 255) & ~(size_t)255;
        void* p = base + off;
        off += bytes;
        return p;
    };
    ushort_t* kvqs = (ushort_t*)alloc((size_t)N_NODES * LDROW * 2);  // ~73 MB
    ushort_t* xb  = (ushort_t*)alloc((size_t)N_NODES * DIM_IN * 2);
    ushort_t* hb0 = (ushort_t*)alloc((size_t)N_NODES * HIDDEN * 2);
    ushort_t* hb1 = (ushort_t*)alloc((size_t)N_NODES * HIDDEN * 2);
    float*    hf  = (float*)alloc((size_t)N_NODES * HIDDEN * 4);
    ushort_t* Wb0 = (ushort_t*)alloc((size_t)DIM_IN * NALL * 2);
    ushort_t* Wbr = (ushort_t*)alloc((size_t)4 * HIDDEN * NALL * 2);
    int*   deg     = (int*)alloc(N_NODES * 4);
    int*   row_ptr = (int*)alloc((N_NODES + 1) * 4);
    int*   cursor  = (int*)alloc(N_NODES * 4);
    int*   csrc    = (int*)alloc(N_EDGES * 4);
    float* gsum    = (float*)alloc(NGRAPH * HIDDEN * 4);
    int*   gcnt    = (int*)alloc(NGRAPH * 4);

    // bf16 conversions (weights transposed)
    k_cvt<<<(N_NODES * DIM_IN + 255) / 256, 256, 0, stream>>>(x, xb, N_NODES * DIM_IN);
    k_cvt_wT<<<(DIM_IN * NALL + 255) / 256, 256, 0, stream>>>(Wq1, Wk1, Wv1, Ws1, DIM_IN, Wb0);
    for (int i = 0; i < 4; i++) {
        k_cvt_wT<<<(HIDDEN * NALL + 255) / 256, 256, 0, stream>>>(
            Wq_r + (size_t)i * HIDDEN * HD, Wk_r + (size_t)i * HIDDEN * HD,
            Wv_r + (size_t)i * HIDDEN * HD, Ws_r + (size_t)i * HIDDEN * HIDDEN,
            HIDDEN, Wbr + (size_t)i * HIDDEN * NALL);
    }

    // CSR by destination
    hipMemsetAsync(deg, 0, N_NODES * 4, stream);
    k_deg<<<(N_EDGES + 255) / 256, 256, 0, stream>>>(edst, deg);
    k_scan<<<1, 1024, 0, stream>>>(deg, row_ptr, cursor);
    k_scatter<<<(N_EDGES + 255) / 256, 256, 0, stream>>>(esrc, edst, cursor, csrc);

    const ushort_t* Ain = xb;
    ushort_t* hbcur = hb0;
    for (int L = 0; L < 5; L++) {
        const ushort_t* Wb = (L == 0) ? Wb0 : (Wbr + (size_t)(L - 1) * HIDDEN * NALL);
        const float *bq, *bk, *bv, *bs;
        if (L == 0) { bq = bq1; bk = bk1; bv = bv1; bs = bs1; }
        else {
            int i = L - 1;
            bq = bq_r + (size_t)i * HD; bk = bk_r + (size_t)i * HD;
            bv = bv_r + (size_t)i * HD; bs = bs_r + (size_t)i * HIDDEN;
        }
        dim3 g(19, (N_NODES + 127) / 128);
        if (L == 0)
            gemm_qkvs_mfma<DIM_IN><<<g, 256, 0, stream>>>(Ain, N_NODES, Wb,
                                                          bq, bk, bv, bs, kvqs);
        else
            gemm_qkvs_mfma<HIDDEN><<<g, 256, 0, stream>>>(Ain, N_NODES, Wb,
                                                          bq, bk, bv, bs, kvqs);
        node_attn<<<N_NODES, 192, 0, stream>>>(kvqs, row_ptr, csrc, hbcur, hf);
        Ain = hbcur;
        hbcur = (hbcur == hb0) ? hb1 : hb0;
    }

    hipMemsetAsync(gsum, 0, NGRAPH * HIDDEN * 4, stream);
    hipMemsetAsync(gcnt, 0, NGRAPH * 4, stream);
    k_pool<<<((N_NODES * HIDDEN) + 255) / 256, 256, 0, stream>>>(hf, batch, gsum, gcnt);
    k_head<<<NGRAPH, 128, 0, stream>>>(gsum, gcnt, fc1w, fc1b, fc2w, fc2b, arcw, out);
}

// Round 8
// 662.826 us; speedup vs baseline: 1.3774x; 1.3774x over previous
//
#include <hip/hip_runtime.h>
#include <math.h>

#define N_NODES 20000
#define N_EDGES 160000
#define DIM_IN  128
#define HIDDEN  96
#define NH      6
#define HD      576      // NH*HIDDEN
#define LDROW   1824     // bf16 row: Q(576) | K(576) | V(576) | S(96)
#define NALL    1824     // concat QKVS output cols
#define NGRAPH  512
#define NCLS    128
#define CHUNK   32       // edges per softmax chunk
#define SLD     104      // LDS stage row stride (ushorts)

typedef unsigned short ushort_t;
typedef __attribute__((ext_vector_type(8))) short bf16x8;
typedef __attribute__((ext_vector_type(4))) float f32x4;

static __device__ __forceinline__ ushort_t f2bf(float f) {
    unsigned int u = __float_as_uint(f);
    return (ushort_t)((u + 0x7fffu + ((u >> 16) & 1u)) >> 16);  // RNE
}
static __device__ __forceinline__ float bfs(ushort_t u) { return __uint_as_float((unsigned int)u << 16); }
static __device__ __forceinline__ float bflo(unsigned int u) { return __uint_as_float(u << 16); }
static __device__ __forceinline__ float bfhi(unsigned int u) { return __uint_as_float(u & 0xffff0000u); }

// ---------------------------------------------------------------------------
__global__ void k_cvt(const float* __restrict__ src, ushort_t* __restrict__ dst, int n)
{
    int i = blockIdx.x * blockDim.x + threadIdx.x;
    if (i < n) dst[i] = f2bf(src[i]);
}

// Build TRANSPOSED concat bf16 weights: WbT[n][k] = W*(k, n), n in [0,1824)
__global__ void k_cvt_wT(const float* __restrict__ Wq, const float* __restrict__ Wk,
                         const float* __restrict__ Wv, const float* __restrict__ Ws,
                         int K, ushort_t* __restrict__ dst)
{
    int i = blockIdx.x * blockDim.x + threadIdx.x;
    if (i >= K * NALL) return;
    int n = i / K, k = i - n * K;
    float v;
    if (n < 576)       v = Wq[(size_t)k * HD + n];
    else if (n < 1152) v = Wk[(size_t)k * HD + (n - 576)];
    else if (n < 1728) v = Wv[(size_t)k * HD + (n - 1152)];
    else               v = Ws[(size_t)k * HIDDEN + (n - 1728)];
    dst[i] = f2bf(v);
}

// ---------------------------------------------------------------------------
// bf16 MFMA fused QKVS projection. Block 128(M) x 96(N), 4 waves (2x2), each
// 64x48 via 4x3 mfma_f32_16x16x32_bf16. B pre-transposed -> staging is pure
// uint4 copies. Epilogue: bias + bf16 LDS stage (aliasing As) + uint4 stores.
// grid.x = 19 col-blocks of 96 -> one bf16 output row kvqs[1824] = Q|K|V|S.
// ---------------------------------------------------------------------------
template<int KDIM>
__global__ __launch_bounds__(256) void gemm_qkvs_mfma(
    const ushort_t* __restrict__ A, int M,
    const ushort_t* __restrict__ WbT,
    const float* __restrict__ bq, const float* __restrict__ bk,
    const float* __restrict__ bv, const float* __restrict__ bs,
    ushort_t* __restrict__ kvqs)
{
    constexpr int LDA = KDIM + 8;
    constexpr int K8  = KDIM >> 3;
    __shared__ __align__(16) ushort_t As[128 * LDA];   // >= 128*SLD for stage
    __shared__ __align__(16) ushort_t Bs[96 * LDA];
    const int t    = threadIdx.x;
    const int lane = t & 63;
    const int w    = t >> 6;
    const int wm   = w & 1, wn = w >> 1;
    const int quad = lane >> 4;
    const int l16  = lane & 15;
    const int m0   = blockIdx.y * 128;
    const int rb   = blockIdx.x;          // 0..18
    const int n0   = rb * 96;

    // stage A tile [128 x K] bf16
    for (int idx = t; idx < 128 * K8; idx += 256) {
        int r = idx / K8, kc = idx - r * K8;
        int row = m0 + r;
        uint4 v = make_uint4(0u, 0u, 0u, 0u);
        if (row < M) v = *(const uint4*)(A + (size_t)row * KDIM + kc * 8);
        *(uint4*)(&As[r * LDA + kc * 8]) = v;
    }
    // stage B tile [96 x K] from transposed weights: pure vector copies
    for (int idx = t; idx < 96 * K8; idx += 256) {
        int c = idx / K8, kc = idx - c * K8;
        uint4 v = *(const uint4*)(WbT + (size_t)(n0 + c) * KDIM + kc * 8);
        *(uint4*)(&Bs[c * LDA + kc * 8]) = v;
    }
    __syncthreads();

    f32x4 acc[4][3] = {};
    #pragma unroll
    for (int ks = 0; ks < KDIM; ks += 32) {
        bf16x8 af[4], bfv[3];
        #pragma unroll
        for (int i = 0; i < 4; i++)
            af[i] = *(const bf16x8*)(&As[(wm * 64 + i * 16 + l16) * LDA + ks + quad * 8]);
        #pragma unroll
        for (int j = 0; j < 3; j++)
            bfv[j] = *(const bf16x8*)(&Bs[(wn * 48 + j * 16 + l16) * LDA + ks + quad * 8]);
        #pragma unroll
        for (int i = 0; i < 4; i++)
            #pragma unroll
            for (int j = 0; j < 3; j++)
                acc[i][j] = __builtin_amdgcn_mfma_f32_16x16x32_bf16(af[i], bfv[j], acc[i][j], 0, 0, 0);
    }

    // bias select (region boundaries are multiples of 96)
    const float* biasp;
    int cb0;
    if (rb < 6)       { biasp = bq; cb0 = n0; }
    else if (rb < 12) { biasp = bk; cb0 = n0 - 576; }
    else if (rb < 18) { biasp = bv; cb0 = n0 - 1152; }
    else              { biasp = bs; cb0 = 0; }
    float bj[3];
    #pragma unroll
    for (int j = 0; j < 3; j++) bj[j] = biasp[cb0 + wn * 48 + j * 16 + l16];

    // stage results bf16 into As (aliased)
    __syncthreads();
    ushort_t* stage = As;
    #pragma unroll
    for (int i = 0; i < 4; i++) {
        #pragma unroll
        for (int r = 0; r < 4; r++) {
            int row = wm * 64 + i * 16 + quad * 4 + r;
            #pragma unroll
            for (int j = 0; j < 3; j++)
                stage[row * SLD + wn * 48 + j * 16 + l16] = f2bf(acc[i][j][r] + bj[j]);
        }
    }
    __syncthreads();

    // cooperative coalesced store: 128 rows x 12 uint4
    for (int idx = t; idx < 128 * 12; idx += 256) {
        int r = idx / 12, v = idx - r * 12;
        int row = m0 + r;
        if (row < M)
            *(uint4*)(kvqs + (size_t)row * LDROW + n0 + v * 8) =
                *(const uint4*)(&stage[r * SLD + v * 8]);
    }
}

// ---------------------------------------------------------------------------
// CSR construction by destination node
// ---------------------------------------------------------------------------
__global__ void k_deg(const int* __restrict__ edst, int* __restrict__ deg)
{
    int e = blockIdx.x * blockDim.x + threadIdx.x;
    if (e < N_EDGES) atomicAdd(&deg[edst[e]], 1);
}

__global__ __launch_bounds__(1024) void k_scan(const int* __restrict__ deg,
                                               int* __restrict__ row_ptr,
                                               int* __restrict__ cursor)
{
    __shared__ int part[1024];
    int t = threadIdx.x;
    const int chunk = (N_NODES + 1023) / 1024;  // 20
    int b = t * chunk;
    int s = 0;
    for (int i = 0; i < chunk; i++)
        if (b + i < N_NODES) s += deg[b + i];
    part[t] = s;
    __syncthreads();
    for (int o = 1; o < 1024; o <<= 1) {
        int v = (t >= o) ? part[t - o] : 0;
        __syncthreads();
        part[t] += v;
        __syncthreads();
    }
    int run = part[t] - s;
    for (int i = 0; i < chunk; i++) {
        if (b + i < N_NODES) {
            row_ptr[b + i] = run;
            cursor[b + i]  = run;
            run += deg[b + i];
        }
    }
    if (t == 1023) row_ptr[N_NODES] = part[1023];
}

__global__ void k_scatter(const int* __restrict__ esrc, const int* __restrict__ edst,
                          int* __restrict__ cursor, int* __restrict__ csrc)
{
    int e = blockIdx.x * blockDim.x + threadIdx.x;
    if (e < N_EDGES) {
        int pos = atomicAdd(&cursor[edst[e]], 1);
        csrc[pos] = esrc[e];
    }
}

// ---------------------------------------------------------------------------
// Fused per-destination-node attention.
// pass 1: 4 lanes per edge, each a 24-elem partial K-dot (3 uint4) + 2 shfl.
// softmax: per-head 32-lane shfl reductions (max & sum fused, one barrier).
// pass 2: thread t<144 owns V elements 4t..4t+3 (one head) -> uint2 loads,
//         compile-time unroll-4 register staging (NO dynamic arrays).
// ---------------------------------------------------------------------------
__global__ __launch_bounds__(192) void node_attn(
    const ushort_t* __restrict__ kvqs,
    const int* __restrict__ row_ptr, const int* __restrict__ csrc,
    ushort_t* __restrict__ hb, float* __restrict__ hf)
{
    const int n = blockIdx.x;
    const int t = threadIdx.x;
    const int lane = t & 31;
    const int g = t >> 5;              // head group 0..5
    const int el = lane >> 2;          // edge slot 0..7
    const int qr = lane & 3;           // quarter 0..3

    __shared__ float Qs[HD];
    __shared__ float wbuf[CHUNK * NH];
    __shared__ int   srcs[CHUNK];
    __shared__ float m[NH], l[NH], scale[NH], linv[NH];
    __shared__ float arr[HD];

    const int beg = row_ptr[n], end = row_ptr[n + 1];
    const ushort_t* qk = kvqs + (size_t)n * LDROW;

    // vectorized Q stage: 72 threads x uint4 (8 bf16 each)
    if (t < 72) {
        uint4 v = *(const uint4*)(qk + t * 8);
        unsigned int uu[4] = {v.x, v.y, v.z, v.w};
        #pragma unroll
        for (int j = 0; j < 4; j++) {
            Qs[t * 8 + 2 * j]     = bflo(uu[j]);
            Qs[t * 8 + 2 * j + 1] = bfhi(uu[j]);
        }
    }
    if (t < NH) { m[t] = -1e30f; l[t] = 0.f; }

    // pass-2 ownership: t<144 owns d = 4t..4t+3 (all in head hh)
    const int d4 = 4 * t;
    const int hh = d4 / HIDDEN;        // valid for t<144
    float a[4] = {0.f, 0.f, 0.f, 0.f};
    const float qa = 0.10206207261596577f; // 1/sqrt(96)

    for (int cb = beg; cb < end; cb += CHUNK) {
        const int c = min(CHUNK, end - cb);
        __syncthreads();
        if (t < c) srcs[t] = csrc[cb + t];
        __syncthreads();

        // ---- pass 1: logits, 4 lanes per edge ---------------------------
        for (int eb = 0; eb < c; eb += 8) {
            int e8 = eb + el;
            bool act = e8 < c;
            int src = srcs[act ? e8 : 0];
            const uint4* kp = (const uint4*)(kvqs + (size_t)src * LDROW + HD + g * HIDDEN + qr * 24);
            uint4 r0 = kp[0], r1 = kp[1], r2 = kp[2];
            const float* qb = &Qs[g * HIDDEN + qr * 24];
            float p = 0.f;
            unsigned int uu[12] = {r0.x, r0.y, r0.z, r0.w, r1.x, r1.y, r1.z, r1.w,
                                   r2.x, r2.y, r2.z, r2.w};
            #pragma unroll
            for (int k2 = 0; k2 < 12; k2++)
                p += bflo(uu[k2]) * qb[2 * k2] + bfhi(uu[k2]) * qb[2 * k2 + 1];
            p += __shfl_xor(p, 1, 32);
            p += __shfl_xor(p, 2, 32);
            if (act && qr == 0) wbuf[e8 * NH + g] = p * qa;
        }
        __syncthreads();

        // ---- fused softmax: head g handled by its 32 lanes --------------
        {
            float logit = (lane < c) ? wbuf[lane * NH + g] : -1e30f;
            float cm = logit;
            #pragma unroll
            for (int o = 16; o; o >>= 1) cm = fmaxf(cm, __shfl_xor(cm, o, 32));
            cm = fmaxf(cm, m[g]);
            float wv = (lane < c) ? __expf(logit - cm) : 0.f;
            if (lane < c) wbuf[lane * NH + g] = wv;
            float lp = wv;
            #pragma unroll
            for (int o = 16; o; o >>= 1) lp += __shfl_xor(lp, o, 32);
            if (lane == 0) {
                float sc = __expf(m[g] - cm);
                scale[g] = sc;
                l[g] = l[g] * sc + lp;
                m[g] = cm;
            }
        }
        __syncthreads();

        // ---- pass 2: V aggregation, unroll-4 register staging -----------
        if (t < 144) {
            float sc = scale[hh];
            #pragma unroll
            for (int j = 0; j < 4; j++) a[j] *= sc;
            const ushort_t* vbase = kvqs + 2 * HD + d4;
            int e = 0;
            for (; e + 4 <= c; e += 4) {
                uint2 r[4];
                #pragma unroll
                for (int j = 0; j < 4; j++)
                    r[j] = *(const uint2*)(vbase + (size_t)srcs[e + j] * LDROW);
                #pragma unroll
                for (int j = 0; j < 4; j++) {
                    float w2 = wbuf[(e + j) * NH + hh];
                    a[0] += w2 * bflo(r[j].x);
                    a[1] += w2 * bfhi(r[j].x);
                    a[2] += w2 * bflo(r[j].y);
                    a[3] += w2 * bfhi(r[j].y);
                }
            }
            for (; e < c; e++) {
                uint2 v = *(const uint2*)(vbase + (size_t)srcs[e] * LDROW);
                float w2 = wbuf[e * NH + hh];
                a[0] += w2 * bflo(v.x);
                a[1] += w2 * bfhi(v.x);
                a[2] += w2 * bflo(v.y);
                a[3] += w2 * bfhi(v.y);
            }
        }
    }

    if (t < NH) linv[t] = (l[t] > 0.f) ? 1.0f / l[t] : 0.f;
    __syncthreads();
    if (t < 144) {
        float li = linv[hh];
        #pragma unroll
        for (int j = 0; j < 4; j++) arr[d4 + j] = a[j] * li;
    }
    __syncthreads();

    if (t < HIDDEN) {
        float s = (arr[t] + arr[HIDDEN + t] + arr[2 * HIDDEN + t] +
                   arr[3 * HIDDEN + t] + arr[4 * HIDDEN + t] + arr[5 * HIDDEN + t])
                  * (1.0f / 6.0f);
        s += bfs(qk[3 * HD + t]);   // skip connection S (bf16)
        s = fmaxf(s, 0.0f);
        hb[n * HIDDEN + t] = f2bf(s);
        hf[n * HIDDEN + t] = s;
    }
}

// ---------------------------------------------------------------------------
__global__ void k_pool(const float* __restrict__ h, const int* __restrict__ batch,
                       float* __restrict__ gsum, int* __restrict__ gcnt)
{
    int i = blockIdx.x * blockDim.x + threadIdx.x;
    if (i >= N_NODES * HIDDEN) return;
    int n = i / HIDDEN, d = i - n * HIDDEN;
    int b = batch[n];
    atomicAdd(&gsum[b * HIDDEN + d], h[i]);
    if (d == 0) atomicAdd(&gcnt[b], 1);
}

__global__ __launch_bounds__(128) void k_head(
    const float* __restrict__ gsum, const int* __restrict__ gcnt,
    const float* __restrict__ fc1w, const float* __restrict__ fc1b,
    const float* __restrict__ fc2w, const float* __restrict__ fc2b,
    const float* __restrict__ arcw, float* __restrict__ out)
{
    int g = blockIdx.x, t = threadIdx.x;
    __shared__ float v0[HIDDEN], v1[HIDDEN], v2[HIDDEN];
    __shared__ float gnorm;
    float cnt = fmaxf((float)gcnt[g], 1.0f);
    if (t < HIDDEN) v0[t] = gsum[g * HIDDEN + t] / cnt;
    __syncthreads();
    if (t < HIDDEN) {
        float s = fc1b[t];
        for (int k = 0; k < HIDDEN; k++) s += v0[k] * fc1w[k * HIDDEN + t];
        v1[t] = fmaxf(s, 0.f);
    }
    __syncthreads();
    if (t < HIDDEN) {
        float s = fc2b[t];
        for (int k = 0; k < HIDDEN; k++) s += v1[k] * fc2w[k * HIDDEN + t];
        v2[t] = fmaxf(s, 0.f);
    }
    __syncthreads();
    if (t == 0) {
        float s = 0.f;
        for (int k = 0; k < HIDDEN; k++) s += v2[k] * v2[k];
        gnorm = sqrtf(s) + 1e-12f;
    }
    __syncthreads();
    if (t < NCLS) {
        float dot = 0.f, wn = 0.f;
        const float* wr = arcw + (size_t)t * HIDDEN;
        for (int k = 0; k < HIDDEN; k++) {
            float w = wr[k];
            dot += w * v2[k];
            wn  += w * w;
        }
        out[g * NCLS + t] = 30.0f * dot / (gnorm * (sqrtf(wn) + 1e-12f));
    }
}

// ---------------------------------------------------------------------------
extern "C" void kernel_launch(void* const* d_in, const int* in_sizes, int n_in,
                              void* d_out, int out_size, void* d_ws, size_t ws_size,
                              hipStream_t stream)
{
    (void)in_sizes; (void)n_in; (void)out_size; (void)ws_size;

    const float* x     = (const float*)d_in[0];
    const int*   ei    = (const int*)d_in[1];
    const int*   batch = (const int*)d_in[2];
    const float* Wq1 = (const float*)d_in[3];  const float* bq1 = (const float*)d_in[4];
    const float* Wk1 = (const float*)d_in[5];  const float* bk1 = (const float*)d_in[6];
    const float* Wv1 = (const float*)d_in[7];  const float* bv1 = (const float*)d_in[8];
    const float* Ws1 = (const float*)d_in[9];  const float* bs1 = (const float*)d_in[10];
    const float* Wq_r = (const float*)d_in[11]; const float* bq_r = (const float*)d_in[12];
    const float* Wk_r = (const float*)d_in[13]; const float* bk_r = (const float*)d_in[14];
    const float* Wv_r = (const float*)d_in[15]; const float* bv_r = (const float*)d_in[16];
    const float* Ws_r = (const float*)d_in[17]; const float* bs_r = (const float*)d_in[18];
    const float* fc1w = (const float*)d_in[19]; const float* fc1b = (const float*)d_in[20];
    const float* fc2w = (const float*)d_in[21]; const float* fc2b = (const float*)d_in[22];
    const float* arcw = (const float*)d_in[23];
    float* out = (float*)d_out;

    const int* esrc = ei;
    const int* edst = ei + N_EDGES;

    char* base = (char*)d_ws;
    size_t off = 0;
    auto alloc = [&](size_t bytes) -> void* {
        off = (off + 255) & ~(size_t)255;
        void* p = base + off;
        off += bytes;
        return p;
    };
    ushort_t* kvqs = (ushort_t*)alloc((size_t)N_NODES * LDROW * 2);  // ~73 MB
    ushort_t* xb  = (ushort_t*)alloc((size_t)N_NODES * DIM_IN * 2);
    ushort_t* hb0 = (ushort_t*)alloc((size_t)N_NODES * HIDDEN * 2);
    ushort_t* hb1 = (ushort_t*)alloc((size_t)N_NODES * HIDDEN * 2);
    float*    hf  = (float*)alloc((size_t)N_NODES * HIDDEN * 4);
    ushort_t* Wb0 = (ushort_t*)alloc((size_t)DIM_IN * NALL * 2);
    ushort_t* Wbr = (ushort_t*)alloc((size_t)4 * HIDDEN * NALL * 2);
    int*   deg     = (int*)alloc(N_NODES * 4);
    int*   row_ptr = (int*)alloc((N_NODES + 1) * 4);
    int*   cursor  = (int*)alloc(N_NODES * 4);
    int*   csrc    = (int*)alloc(N_EDGES * 4);
    float* gsum    = (float*)alloc(NGRAPH * HIDDEN * 4);
    int*   gcnt    = (int*)alloc(NGRAPH * 4);

    // bf16 conversions (weights transposed)
    k_cvt<<<(N_NODES * DIM_IN + 255) / 256, 256, 0, stream>>>(x, xb, N_NODES * DIM_IN);
    k_cvt_wT<<<(DIM_IN * NALL + 255) / 256, 256, 0, stream>>>(Wq1, Wk1, Wv1, Ws1, DIM_IN, Wb0);
    for (int i = 0; i < 4; i++) {
        k_cvt_wT<<<(HIDDEN * NALL + 255) / 256, 256, 0, stream>>>(
            Wq_r + (size_t)i * HIDDEN * HD, Wk_r + (size_t)i * HIDDEN * HD,
            Wv_r + (size_t)i * HIDDEN * HD, Ws_r + (size_t)i * HIDDEN * HIDDEN,
            HIDDEN, Wbr + (size_t)i * HIDDEN * NALL);
    }

    // CSR by destination
    hipMemsetAsync(deg, 0, N_NODES * 4, stream);
    k_deg<<<(N_EDGES + 255) / 256, 256, 0, stream>>>(edst, deg);
    k_scan<<<1, 1024, 0, stream>>>(deg, row_ptr, cursor);
    k_scatter<<<(N_EDGES + 255) / 256, 256, 0, stream>>>(esrc, edst, cursor, csrc);

    const ushort_t* Ain = xb;
    ushort_t* hbcur = hb0;
    for (int L = 0; L < 5; L++) {
        const ushort_t* Wb = (L == 0) ? Wb0 : (Wbr + (size_t)(L - 1) * HIDDEN * NALL);
        const float *bq, *bk, *bv, *bs;
        if (L == 0) { bq = bq1; bk = bk1; bv = bv1; bs = bs1; }
        else {
            int i = L - 1;
            bq = bq_r + (size_t)i * HD; bk = bk_r + (size_t)i * HD;
            bv = bv_r + (size_t)i * HD; bs = bs_r + (size_t)i * HIDDEN;
        }
        dim3 g(19, (N_NODES + 127) / 128);
        if (L == 0)
            gemm_qkvs_mfma<DIM_IN><<<g, 256, 0, stream>>>(Ain, N_NODES, Wb,
                                                          bq, bk, bv, bs, kvqs);
        else
            gemm_qkvs_mfma<HIDDEN><<<g, 256, 0, stream>>>(Ain, N_NODES, Wb,
                                                          bq, bk, bv, bs, kvqs);
        node_attn<<<N_NODES, 192, 0, stream>>>(kvqs, row_ptr, csrc, hbcur, hf);
        Ain = hbcur;
        hbcur = (hbcur == hb0) ? hb1 : hb0;
    }

    hipMemsetAsync(gsum, 0, NGRAPH * HIDDEN * 4, stream);
    hipMemsetAsync(gcnt, 0, NGRAPH * 4, stream);
    k_pool<<<((N_NODES * HIDDEN) + 255) / 256, 256, 0, stream>>>(hf, batch, gsum, gcnt);
    k_head<<<NGRAPH, 128, 0, stream>>>(gsum, gcnt, fc1w, fc1b, fc2w, fc2b, arcw, out);
}